// Round 2
// baseline (583.175 us; speedup 1.0000x reference)
//
#include <hip/hip_runtime.h>
#include <math.h>

#define BATCH 512
#define DIM 512
#define NCLASS 100000
#define BN 64
#define NT 1563              /* ceil(100000/64) */
#define NBLOCKS 256
#define S_SCALE 30.0f
#define COSM 0.8775825618903728f
#define SINM 0.4794255386042030f

typedef unsigned short u16;
typedef __attribute__((ext_vector_type(8))) short short8;
typedef __attribute__((ext_vector_type(4))) float floatx4;

// ws layout (bytes):
//   [0, 524288)            xn bf16 [512][512]
//   [524288, 526336)       tlogit float[512]
//   [526336, 528384)       nll    float[512]
//   [528384, +512*NT*4)    partials [512][NT]  (~3.2 MB; total ~3.73 MB)

__device__ __forceinline__ u16 f2bf(float f) {
    union { float f; unsigned int u; } v;
    v.f = f;
    unsigned int u = v.u;
    u += 0x7fffu + ((u >> 16) & 1u);   // round-to-nearest-even
    return (u16)(u >> 16);
}

// ---------------- Kernel 1: normalize x rows -> bf16 ----------------
__global__ void xnorm_kernel(const float* __restrict__ x, u16* __restrict__ xn) {
    const int row = blockIdx.x;
    const int t = threadIdx.x; // 64 threads = 1 wave
    const floatx4* xr = (const floatx4*)(x + (size_t)row * DIM);
    floatx4 a = xr[t];
    floatx4 b = xr[t + 64];
    float ss = a[0]*a[0] + a[1]*a[1] + a[2]*a[2] + a[3]*a[3]
             + b[0]*b[0] + b[1]*b[1] + b[2]*b[2] + b[3]*b[3];
#pragma unroll
    for (int d = 1; d < 64; d <<= 1) ss += __shfl_xor(ss, d);
    const float rn = 1.0f / fmaxf(sqrtf(ss), 1e-12f);
    ushort4 ua, ub;
    ua.x = f2bf(a[0]*rn); ua.y = f2bf(a[1]*rn); ua.z = f2bf(a[2]*rn); ua.w = f2bf(a[3]*rn);
    ub.x = f2bf(b[0]*rn); ub.y = f2bf(b[1]*rn); ub.z = f2bf(b[2]*rn); ub.w = f2bf(b[3]*rn);
    u16* orow = xn + (size_t)row * DIM;
    *(ushort4*)(orow + 4*t)       = ua;
    *(ushort4*)(orow + 256 + 4*t) = ub;
}

// ---- staging helpers (w fp32 -> normalized bf16 in LDS, XOR-swizzled 16B granules) ----
__device__ __forceinline__ void stage_issue(const float* __restrict__ w, int cg, int sq,
                                            floatx4* v) {
    if (cg < NCLASS) {
        const floatx4* wr = (const floatx4*)(w + (size_t)cg * DIM);
#pragma unroll
        for (int j = 0; j < 16; ++j) v[j] = wr[sq + (j << 3)];
    } else {
#pragma unroll
        for (int j = 0; j < 16; ++j) { v[j][0]=0.f; v[j][1]=0.f; v[j][2]=0.f; v[j][3]=0.f; }
    }
}

__device__ __forceinline__ void stage_commit(const floatx4* v, int sr, int sq,
                                             u16* wb) {
    float ss = 0.f;
#pragma unroll
    for (int j = 0; j < 16; ++j)
        ss += v[j][0]*v[j][0] + v[j][1]*v[j][1] + v[j][2]*v[j][2] + v[j][3]*v[j][3];
    // reduce across the 8 threads of this row (lane bits 0..2)
    ss += __shfl_xor(ss, 1);
    ss += __shfl_xor(ss, 2);
    ss += __shfl_xor(ss, 4);
    const float rs = 1.0f / fmaxf(sqrtf(ss), 1e-12f);
#pragma unroll
    for (int j = 0; j < 16; ++j) {
        const int col4 = sq + (j << 3);
        const int gp = (col4 >> 1) ^ (sr & 7);       // swizzled 16B granule
        const int off = sr * DIM + gp * 8 + (col4 & 1) * 4;
        ushort4 u;
        u.x = f2bf(v[j][0] * rs); u.y = f2bf(v[j][1] * rs);
        u.z = f2bf(v[j][2] * rs); u.w = f2bf(v[j][3] * rs);
        *(ushort4*)(&wb[off]) = u;
    }
}

// ---------------- Kernel 2: persistent fused GEMM + partial softmax ----------------
// grid = 256 blocks x 512 threads, ~1 block/CU. Block b handles class tiles
// {b, b+256, ...} (6 or 7 tiles). Register-double-buffered w staging overlaps
// the HBM fetch of tile t+1 with the MFMA phase of tile t.
__global__ __launch_bounds__(512, 2)
void arcface_main(const float* __restrict__ w,
                  const u16* __restrict__ xn,
                  const int* __restrict__ target,
                  float* __restrict__ partials,
                  float* __restrict__ tlogit) {
    __shared__ u16 wb[BN * DIM]; // 65536 B

    const int t = threadIdx.x;
    const int bid = blockIdx.x;
    const int cnt = (bid < (NT % NBLOCKS)) ? (NT / NBLOCKS + 1) : (NT / NBLOCKS);

    const int sr = t >> 3;       // stage row 0..63
    const int sq = t & 7;        // 8 threads per row

    const int wave = t >> 6;     // 0..7 -> m range [wave*64, +64)
    const int lane = t & 63;
    const int quad = lane >> 4;  // 0..3
    const int nin  = lane & 15;  // 0..15
    const int mbase = wave * 64;

    // hoist target values for this lane's 16 output rows
    int tgv[4][4];
#pragma unroll
    for (int mi = 0; mi < 4; ++mi)
#pragma unroll
        for (int reg = 0; reg < 4; ++reg)
            tgv[mi][reg] = target[mbase + mi * 16 + quad * 4 + reg];

    floatx4 v[16];

    // ---- prologue: stage tile 0 ----
    stage_issue(w, bid * BN + sr, sq, v);
    stage_commit(v, sr, sq, wb);
    __syncthreads();

    for (int i = 0; i < cnt; ++i) {
        const int tile = bid + i * NBLOCKS;
        const int c0 = tile * BN;
        const bool hasNext = (i + 1 < cnt);

        // issue global loads for next tile NOW; they complete during MFMA phase
        if (hasNext)
            stage_issue(w, (bid + (i + 1) * NBLOCKS) * BN + sr, sq, v);

        // ---- MFMA phase (2-stage software-pipelined kk loop) ----
        floatx4 acc[4][4];
#pragma unroll
        for (int mi = 0; mi < 4; ++mi)
#pragma unroll
            for (int ni = 0; ni < 4; ++ni) {
                acc[mi][ni][0] = 0.f; acc[mi][ni][1] = 0.f;
                acc[mi][ni][2] = 0.f; acc[mi][ni][3] = 0.f;
            }

        short8 a0[4], b0[4], a1[4], b1[4];
#pragma unroll
        for (int mi = 0; mi < 4; ++mi)
            a0[mi] = *(const short8*)(xn + ((size_t)(mbase + mi * 16 + nin) << 9) + (quad << 3));
#pragma unroll
        for (int ni = 0; ni < 4; ++ni) {
            const int cl = ni * 16 + nin;
            const int gp = quad ^ (cl & 7);
            b0[ni] = *(const short8*)(&wb[(cl << 9) + (gp << 3)]);
        }

#pragma unroll
        for (int kk = 0; kk < 16; kk += 2) {
            // prefetch kk+1
#pragma unroll
            for (int mi = 0; mi < 4; ++mi)
                a1[mi] = *(const short8*)(xn + ((size_t)(mbase + mi * 16 + nin) << 9)
                                              + ((kk + 1) << 5) + (quad << 3));
#pragma unroll
            for (int ni = 0; ni < 4; ++ni) {
                const int cl = ni * 16 + nin;
                const int gp = (((kk + 1) << 2) + quad) ^ (cl & 7);
                b1[ni] = *(const short8*)(&wb[(cl << 9) + (gp << 3)]);
            }
#pragma unroll
            for (int mi = 0; mi < 4; ++mi)
#pragma unroll
                for (int ni = 0; ni < 4; ++ni)
                    acc[mi][ni] = __builtin_amdgcn_mfma_f32_16x16x32_bf16(
                        a0[mi], b0[ni], acc[mi][ni], 0, 0, 0);
            // prefetch kk+2
            if (kk + 2 < 16) {
#pragma unroll
                for (int mi = 0; mi < 4; ++mi)
                    a0[mi] = *(const short8*)(xn + ((size_t)(mbase + mi * 16 + nin) << 9)
                                                  + ((kk + 2) << 5) + (quad << 3));
#pragma unroll
                for (int ni = 0; ni < 4; ++ni) {
                    const int cl = ni * 16 + nin;
                    const int gp = (((kk + 2) << 2) + quad) ^ (cl & 7);
                    b0[ni] = *(const short8*)(&wb[(cl << 9) + (gp << 3)]);
                }
            }
#pragma unroll
            for (int mi = 0; mi < 4; ++mi)
#pragma unroll
                for (int ni = 0; ni < 4; ++ni)
                    acc[mi][ni] = __builtin_amdgcn_mfma_f32_16x16x32_bf16(
                        a1[mi], b1[ni], acc[mi][ni], 0, 0, 0);
        }

        // ---- epilogue: arcface transform + per-row exp-sum ----
        // C/D layout: col(n) = lane&15, row(m) = (lane>>4)*4 + reg
#pragma unroll
        for (int mi = 0; mi < 4; ++mi) {
#pragma unroll
            for (int reg = 0; reg < 4; ++reg) {
                const int m = mbase + mi * 16 + quad * 4 + reg;
                const int tg = tgv[mi][reg];
                float psum = 0.f;
#pragma unroll
                for (int ni = 0; ni < 4; ++ni) {
                    const int c = c0 + ni * 16 + nin;
                    if (c < NCLASS) {
                        const float cosv = acc[mi][ni][reg];
                        float lg = S_SCALE * cosv;
                        if (c == tg) {
                            const float sine = sqrtf(fmaxf(1.f - cosv * cosv, 0.f));
                            float phi = cosv * COSM - sine * SINM;
                            if (!(cosv > 0.f)) phi = cosv;   // easy_margin
                            lg = S_SCALE * phi;
                            tlogit[m] = lg;
                        }
                        psum += __expf(lg - S_SCALE);        // fixed shift S (logit <= S)
                    }
                }
                psum += __shfl_xor(psum, 1);
                psum += __shfl_xor(psum, 2);
                psum += __shfl_xor(psum, 4);
                psum += __shfl_xor(psum, 8);
                if (nin == 0)
                    partials[(size_t)m * NT + tile] = psum;
            }
        }

        __syncthreads();               // all waves done reading wb
        if (hasNext)
            stage_commit(v, sr, sq, wb);
        __syncthreads();               // wb[t+1] visible
    }
}

// ---------------- Kernel 3a: per-row logsumexp + nll (coalesced) ----------------
__global__ void reduce_lse(const float* __restrict__ partials,
                           const float* __restrict__ tlogit,
                           float* __restrict__ nll) {
    const int m = blockIdx.x;
    const int t = threadIdx.x; // 256
    const float* row = partials + (size_t)m * NT;
    float s = 0.f;
    for (int j = t; j < NT; j += 256) s += row[j];
#pragma unroll
    for (int d = 1; d < 64; d <<= 1) s += __shfl_xor(s, d);
    __shared__ float red[4];
    if ((t & 63) == 0) red[t >> 6] = s;
    __syncthreads();
    if (t == 0) {
        const float tot = red[0] + red[1] + red[2] + red[3];
        nll[m] = (logf(tot) + S_SCALE) - tlogit[m];
    }
}

// ---------------- Kernel 3b: mean ----------------
__global__ void reduce_mean(const float* __restrict__ nll, float* __restrict__ out) {
    const int t = threadIdx.x; // 512
    float s = nll[t];
#pragma unroll
    for (int d = 1; d < 64; d <<= 1) s += __shfl_xor(s, d);
    __shared__ float red[8];
    if ((t & 63) == 0) red[t >> 6] = s;
    __syncthreads();
    if (t == 0) {
        float tot = 0.f;
#pragma unroll
        for (int i = 0; i < 8; ++i) tot += red[i];
        out[0] = tot / (float)BATCH;
    }
}

extern "C" void kernel_launch(void* const* d_in, const int* in_sizes, int n_in,
                              void* d_out, int out_size, void* d_ws, size_t ws_size,
                              hipStream_t stream) {
    const float* x = (const float*)d_in[0];
    const float* w = (const float*)d_in[1];
    const int* target = (const int*)d_in[2];

    char* ws = (char*)d_ws;
    u16* xn         = (u16*)ws;
    float* tlogit   = (float*)(ws + 524288);
    float* nll      = (float*)(ws + 526336);
    float* partials = (float*)(ws + 528384);

    xnorm_kernel<<<BATCH, 64, 0, stream>>>(x, xn);
    arcface_main<<<NBLOCKS, 512, 0, stream>>>(w, xn, target, partials, tlogit);
    reduce_lse<<<BATCH, 256, 0, stream>>>(partials, tlogit, nll);
    reduce_mean<<<1, 512, 0, stream>>>(nll, (float*)d_out);
}

// Round 3
// 556.741 us; speedup vs baseline: 1.0475x; 1.0475x over previous
//
#include <hip/hip_runtime.h>
#include <math.h>

#define BATCH 512
#define DIM 512
#define NCLASS 100000
#define BN 64
#define NT 1563              /* ceil(100000/64) */
#define NBLOCKS 256
#define S_SCALE 30.0f
#define COSM 0.8775825618903728f
#define SINM 0.4794255386042030f

typedef unsigned short u16;
typedef __attribute__((ext_vector_type(8))) short short8;
typedef __attribute__((ext_vector_type(4))) float floatx4;

// ws layout (bytes):
//   [0, 524288)            xn bf16 [512][512]
//   [524288, 526336)       tlogit float[512]
//   [526336, 528384)       nll    float[512]
//   [528384, 1052672)      partials [512][NBLOCKS] float  (512 KB; total ~1.0 MB)

__device__ __forceinline__ u16 f2bf(float f) {
    union { float f; unsigned int u; } v;
    v.f = f;
    unsigned int u = v.u;
    u += 0x7fffu + ((u >> 16) & 1u);   // round-to-nearest-even
    return (u16)(u >> 16);
}

// ---------------- Kernel 1: normalize x rows -> bf16 ----------------
__global__ void xnorm_kernel(const float* __restrict__ x, u16* __restrict__ xn) {
    const int row = blockIdx.x;
    const int t = threadIdx.x; // 64 threads = 1 wave
    const floatx4* xr = (const floatx4*)(x + (size_t)row * DIM);
    floatx4 a = xr[t];
    floatx4 b = xr[t + 64];
    float ss = a[0]*a[0] + a[1]*a[1] + a[2]*a[2] + a[3]*a[3]
             + b[0]*b[0] + b[1]*b[1] + b[2]*b[2] + b[3]*b[3];
#pragma unroll
    for (int d = 1; d < 64; d <<= 1) ss += __shfl_xor(ss, d);
    const float rn = 1.0f / fmaxf(sqrtf(ss), 1e-12f);
    ushort4 ua, ub;
    ua.x = f2bf(a[0]*rn); ua.y = f2bf(a[1]*rn); ua.z = f2bf(a[2]*rn); ua.w = f2bf(a[3]*rn);
    ub.x = f2bf(b[0]*rn); ub.y = f2bf(b[1]*rn); ub.z = f2bf(b[2]*rn); ub.w = f2bf(b[3]*rn);
    u16* orow = xn + (size_t)row * DIM;
    *(ushort4*)(orow + 4*t)       = ua;
    *(ushort4*)(orow + 256 + 4*t) = ub;
}

// ---- staging helpers (w fp32 -> normalized bf16 in LDS, XOR-swizzled 16B granules) ----
__device__ __forceinline__ void stage_issue(const float* __restrict__ w, int cg, int sq,
                                            floatx4* v) {
    if (cg < NCLASS) {
        const floatx4* wr = (const floatx4*)(w + (size_t)cg * DIM);
#pragma unroll
        for (int j = 0; j < 16; ++j) v[j] = wr[sq + (j << 3)];
    } else {
#pragma unroll
        for (int j = 0; j < 16; ++j) { v[j][0]=0.f; v[j][1]=0.f; v[j][2]=0.f; v[j][3]=0.f; }
    }
}

__device__ __forceinline__ void stage_commit(const floatx4* v, int sr, int sq,
                                             u16* wb) {
    float ss = 0.f;
#pragma unroll
    for (int j = 0; j < 16; ++j)
        ss += v[j][0]*v[j][0] + v[j][1]*v[j][1] + v[j][2]*v[j][2] + v[j][3]*v[j][3];
    ss += __shfl_xor(ss, 1);
    ss += __shfl_xor(ss, 2);
    ss += __shfl_xor(ss, 4);
    const float rs = 1.0f / fmaxf(sqrtf(ss), 1e-12f);
#pragma unroll
    for (int j = 0; j < 16; ++j) {
        const int col4 = sq + (j << 3);
        const int gp = (col4 >> 1) ^ (sr & 7);       // swizzled 16B granule
        const int off = sr * DIM + gp * 8 + (col4 & 1) * 4;
        ushort4 u;
        u.x = f2bf(v[j][0] * rs); u.y = f2bf(v[j][1] * rs);
        u.z = f2bf(v[j][2] * rs); u.w = f2bf(v[j][3] * rs);
        *(ushort4*)(&wb[off]) = u;
    }
}

// ---------------- Kernel 2: persistent fused GEMM + partial softmax ----------------
// grid = 256 blocks x 512 threads (8 waves), 1 block/CU (register-gated).
// amdgpu_waves_per_eu(2,2): exactly 2 waves/EU -> 256-VGPR budget so the
// v[16] staging buffer + frag pipeline + acc live without spilling (R2's bug).
__global__ __launch_bounds__(512) __attribute__((amdgpu_waves_per_eu(2, 2)))
void arcface_main(const float* __restrict__ w,
                  const u16* __restrict__ xn,
                  const int* __restrict__ target,
                  float* __restrict__ partials,
                  float* __restrict__ tlogit) {
    __shared__ u16 wb[BN * DIM]; // 65536 B

    const int t = threadIdx.x;
    const int bid = blockIdx.x;
    const int cnt = (bid < (NT % NBLOCKS)) ? (NT / NBLOCKS + 1) : (NT / NBLOCKS);

    const int sr = t >> 3;       // stage row 0..63
    const int sq = t & 7;        // 8 threads per row

    const int wave = t >> 6;     // 0..7 -> m range [wave*64, +64)
    const int lane = t & 63;
    const int quad = lane >> 4;  // 0..3
    const int nin  = lane & 15;  // 0..15
    const int mbase = wave * 64;

    float psum_acc[4][4];
#pragma unroll
    for (int mi = 0; mi < 4; ++mi)
#pragma unroll
        for (int reg = 0; reg < 4; ++reg) psum_acc[mi][reg] = 0.f;

    floatx4 v[16];

    // ---- prologue: stage tile 0 ----
    stage_issue(w, bid * BN + sr, sq, v);
    stage_commit(v, sr, sq, wb);
    __syncthreads();

    for (int i = 0; i < cnt; ++i) {
        const int tile = bid + i * NBLOCKS;
        const int c0 = tile * BN;
        const bool hasNext = (i + 1 < cnt);

        // issue global loads for next tile; they complete during the MFMA phase
        if (hasNext)
            stage_issue(w, (bid + (i + 1) * NBLOCKS) * BN + sr, sq, v);

        // ---- MFMA phase (2-stage software-pipelined kk loop) ----
        floatx4 acc[4][4];
#pragma unroll
        for (int mi = 0; mi < 4; ++mi)
#pragma unroll
            for (int ni = 0; ni < 4; ++ni) {
                acc[mi][ni][0] = 0.f; acc[mi][ni][1] = 0.f;
                acc[mi][ni][2] = 0.f; acc[mi][ni][3] = 0.f;
            }

        short8 a0[4], b0[4], a1[4], b1[4];
#pragma unroll
        for (int mi = 0; mi < 4; ++mi)
            a0[mi] = *(const short8*)(xn + ((size_t)(mbase + mi * 16 + nin) << 9) + (quad << 3));
#pragma unroll
        for (int ni = 0; ni < 4; ++ni) {
            const int cl = ni * 16 + nin;
            const int gp = quad ^ (cl & 7);
            b0[ni] = *(const short8*)(&wb[(cl << 9) + (gp << 3)]);
        }

#pragma unroll
        for (int kk = 0; kk < 16; kk += 2) {
#pragma unroll
            for (int mi = 0; mi < 4; ++mi)
                a1[mi] = *(const short8*)(xn + ((size_t)(mbase + mi * 16 + nin) << 9)
                                              + ((kk + 1) << 5) + (quad << 3));
#pragma unroll
            for (int ni = 0; ni < 4; ++ni) {
                const int cl = ni * 16 + nin;
                const int gp = (((kk + 1) << 2) + quad) ^ (cl & 7);
                b1[ni] = *(const short8*)(&wb[(cl << 9) + (gp << 3)]);
            }
#pragma unroll
            for (int mi = 0; mi < 4; ++mi)
#pragma unroll
                for (int ni = 0; ni < 4; ++ni)
                    acc[mi][ni] = __builtin_amdgcn_mfma_f32_16x16x32_bf16(
                        a0[mi], b0[ni], acc[mi][ni], 0, 0, 0);
            if (kk + 2 < 16) {
#pragma unroll
                for (int mi = 0; mi < 4; ++mi)
                    a0[mi] = *(const short8*)(xn + ((size_t)(mbase + mi * 16 + nin) << 9)
                                                  + ((kk + 2) << 5) + (quad << 3));
#pragma unroll
                for (int ni = 0; ni < 4; ++ni) {
                    const int cl = ni * 16 + nin;
                    const int gp = (((kk + 2) << 2) + quad) ^ (cl & 7);
                    b0[ni] = *(const short8*)(&wb[(cl << 9) + (gp << 3)]);
                }
            }
#pragma unroll
            for (int mi = 0; mi < 4; ++mi)
#pragma unroll
                for (int ni = 0; ni < 4; ++ni)
                    acc[mi][ni] = __builtin_amdgcn_mfma_f32_16x16x32_bf16(
                        a1[mi], b1[ni], acc[mi][ni], 0, 0, 0);
        }

        // ---- epilogue: arcface transform + per-row exp-sum (accumulated) ----
        // C/D layout: col(n) = lane&15, row(m) = (lane>>4)*4 + reg
#pragma unroll
        for (int mi = 0; mi < 4; ++mi) {
#pragma unroll
            for (int reg = 0; reg < 4; ++reg) {
                const int m = mbase + mi * 16 + quad * 4 + reg;
                const int tg = target[m];     // 2 KB table, L1-resident
                float psum = 0.f;
#pragma unroll
                for (int ni = 0; ni < 4; ++ni) {
                    const int c = c0 + ni * 16 + nin;
                    if (c < NCLASS) {
                        const float cosv = acc[mi][ni][reg];
                        float lg = S_SCALE * cosv;
                        if (c == tg) {
                            const float sine = sqrtf(fmaxf(1.f - cosv * cosv, 0.f));
                            float phi = cosv * COSM - sine * SINM;
                            if (!(cosv > 0.f)) phi = cosv;   // easy_margin
                            lg = S_SCALE * phi;
                            tlogit[m] = lg;
                        }
                        psum += __expf(lg - S_SCALE);        // fixed shift S (logit <= S)
                    }
                }
                psum += __shfl_xor(psum, 1);
                psum += __shfl_xor(psum, 2);
                psum += __shfl_xor(psum, 4);
                psum += __shfl_xor(psum, 8);
                psum_acc[mi][reg] += psum;   // accumulate across this block's tiles
            }
        }

        __syncthreads();               // all waves done reading wb
        if (hasNext)
            stage_commit(v, sr, sq, wb);
        __syncthreads();               // wb[t+1] visible
    }

    // one write per (m) per block
#pragma unroll
    for (int mi = 0; mi < 4; ++mi)
#pragma unroll
        for (int reg = 0; reg < 4; ++reg) {
            if (nin == 0) {
                const int m = mbase + mi * 16 + quad * 4 + reg;
                partials[(size_t)m * NBLOCKS + bid] = psum_acc[mi][reg];
            }
        }
}

// ---------------- Kernel 3a: per-row logsumexp + nll (coalesced, 256 wide) ----------------
__global__ void reduce_lse(const float* __restrict__ partials,
                           const float* __restrict__ tlogit,
                           float* __restrict__ nll) {
    const int m = blockIdx.x;
    const int t = threadIdx.x; // 64 threads = 1 wave
    const float* row = partials + (size_t)m * NBLOCKS;
    float s = row[t] + row[t + 64] + row[t + 128] + row[t + 192];
#pragma unroll
    for (int d = 1; d < 64; d <<= 1) s += __shfl_xor(s, d);
    if (t == 0)
        nll[m] = (logf(s) + S_SCALE) - tlogit[m];
}

// ---------------- Kernel 3b: mean ----------------
__global__ void reduce_mean(const float* __restrict__ nll, float* __restrict__ out) {
    const int t = threadIdx.x; // 512
    float s = nll[t];
#pragma unroll
    for (int d = 1; d < 64; d <<= 1) s += __shfl_xor(s, d);
    __shared__ float red[8];
    if ((t & 63) == 0) red[t >> 6] = s;
    __syncthreads();
    if (t == 0) {
        float tot = 0.f;
#pragma unroll
        for (int i = 0; i < 8; ++i) tot += red[i];
        out[0] = tot / (float)BATCH;
    }
}

extern "C" void kernel_launch(void* const* d_in, const int* in_sizes, int n_in,
                              void* d_out, int out_size, void* d_ws, size_t ws_size,
                              hipStream_t stream) {
    const float* x = (const float*)d_in[0];
    const float* w = (const float*)d_in[1];
    const int* target = (const int*)d_in[2];

    char* ws = (char*)d_ws;
    u16* xn         = (u16*)ws;
    float* tlogit   = (float*)(ws + 524288);
    float* nll      = (float*)(ws + 526336);
    float* partials = (float*)(ws + 528384);

    xnorm_kernel<<<BATCH, 64, 0, stream>>>(x, xn);
    arcface_main<<<NBLOCKS, 512, 0, stream>>>(w, xn, target, partials, tlogit);
    reduce_lse<<<BATCH, 64, 0, stream>>>(partials, tlogit, nll);
    reduce_mean<<<1, 512, 0, stream>>>(nll, (float*)d_out);
}

// Round 4
// 423.900 us; speedup vs baseline: 1.3757x; 1.3134x over previous
//
#include <hip/hip_runtime.h>
#include <math.h>
#include <stdint.h>

#define BATCH 512
#define DIM 512
#define NCLASS 100000
#define BN 64
#define BK 64
#define NSTEP (DIM / BK)              /* 8 */
#define NT ((NCLASS + BN - 1) / BN)   /* 1563 */
#define S_SCALE 30.0f
#define COSM 0.8775825618903728f
#define SINM 0.4794255386042030f

typedef unsigned short u16;
typedef __attribute__((ext_vector_type(8))) short short8;
typedef __attribute__((ext_vector_type(4))) float floatx4;

// ws layout (bytes):
//   [0, 524288)            xn bf16 [512][512]
//   [524288, 526336)       tlogit float[512]
//   [526336, 528384)       nll    float[512]
//   [528384, +NT*512*4)    partials [NT][512]  (~3.2 MB)

__device__ __forceinline__ u16 f2bf(float f) {
    union { float f; unsigned int u; } v;
    v.f = f;
    unsigned int u = v.u;
    u += 0x7fffu + ((u >> 16) & 1u);   // round-to-nearest-even
    return (u16)(u >> 16);
}

// CK-style addrspace cast idiom for global_load_lds (AS3 ptrs are 32-bit LDS offsets)
__device__ __forceinline__ void async_cp16(const void* g, void* l) {
    auto gp = reinterpret_cast<const __attribute__((address_space(1))) unsigned int*>(
        reinterpret_cast<uintptr_t>(g));
    auto lp = reinterpret_cast<__attribute__((address_space(3))) unsigned int*>(
        reinterpret_cast<uintptr_t>(l));
    __builtin_amdgcn_global_load_lds(gp, lp, 16, 0, 0);  // 16B per lane, lane-linear LDS dest
}

// ---------------- Kernel 1: normalize x rows -> bf16 ----------------
__global__ void xnorm_kernel(const float* __restrict__ x, u16* __restrict__ xn) {
    const int row = blockIdx.x;
    const int t = threadIdx.x; // 64 threads = 1 wave
    const floatx4* xr = (const floatx4*)(x + (size_t)row * DIM);
    floatx4 a = xr[t];
    floatx4 b = xr[t + 64];
    float ss = a[0]*a[0] + a[1]*a[1] + a[2]*a[2] + a[3]*a[3]
             + b[0]*b[0] + b[1]*b[1] + b[2]*b[2] + b[3]*b[3];
#pragma unroll
    for (int d = 1; d < 64; d <<= 1) ss += __shfl_xor(ss, d);
    const float rn = 1.0f / fmaxf(sqrtf(ss), 1e-12f);
    ushort4 ua, ub;
    ua.x = f2bf(a[0]*rn); ua.y = f2bf(a[1]*rn); ua.z = f2bf(a[2]*rn); ua.w = f2bf(a[3]*rn);
    ub.x = f2bf(b[0]*rn); ub.y = f2bf(b[1]*rn); ub.z = f2bf(b[2]*rn); ub.w = f2bf(b[3]*rn);
    u16* orow = xn + (size_t)row * DIM;
    *(ushort4*)(orow + 4*t)       = ua;
    *(ushort4*)(orow + 256 + 4*t) = ub;
}

// ---------------- Kernel 2: fused GEMM + partial softmax ----------------
// grid = NT blocks x 512 threads (8 waves, m-split: wave w owns rows [64w,64w+64)).
// Per K-step (BK=64): DMA fp32 w-slice into LDS (double-buffered, register-free),
// cooperative fp32->bf16 convert (+ per-class sumsq), MFMA on bf16 tile.
// Norms applied in the epilogue: cos = dot(xn, w_bf16) * rsqrt(sumsq).
__global__ void arcface_main(const float* __restrict__ w,
                             const u16* __restrict__ xn,
                             const int* __restrict__ target,
                             float* __restrict__ partials,
                             float* __restrict__ tlogit) {
    __shared__ float fbuf[2][BN * BK];   // 2 x 16 KB raw fp32 w slices
    __shared__ u16   bbuf[BN * BK];      // 8 KB bf16 tile (16B-granule XOR swizzle)
    __shared__ float ssb[BN];            // per-class sum of squares

    const int t = threadIdx.x;
    const int tile = blockIdx.x;
    const int c0 = tile * BN;

    const int wave = t >> 6;
    const int lane = t & 63;
    const int quad = lane >> 4;
    const int nin  = lane & 15;
    const int mbase = wave * 64;

    // --- staging addresses: 2 DMA calls per wave per step, lane-linear LDS ---
    // flat fp32 granule gi = wave*128 + j*64 + lane ; cl = gi>>4 ; gq = gi&15
    size_t goff[2];
    int ldsoff[2];
#pragma unroll
    for (int j = 0; j < 2; ++j) {
        const int gi = wave * 128 + j * 64 + lane;
        const int cl = gi >> 4, gq = gi & 15;
        int cls = c0 + cl; if (cls > NCLASS - 1) cls = NCLASS - 1;  // clamp tail tile
        goff[j] = (size_t)cls * (DIM * 4) + (size_t)gq * 16;
        ldsoff[j] = wave * 2048 + j * 1024;   // + lane*16 implicit in the DMA
    }
    const char* wbytes = (const char*)w;

    // issue DMA for step 0 into fbuf[0]
#pragma unroll
    for (int j = 0; j < 2; ++j)
        async_cp16(wbytes + goff[j], (char*)&fbuf[0][0] + ldsoff[j]);

    if (t < BN) ssb[t] = 0.f;

    floatx4 acc[4][4];
#pragma unroll
    for (int mi = 0; mi < 4; ++mi)
#pragma unroll
        for (int ni = 0; ni < 4; ++ni) {
            acc[mi][ni][0] = 0.f; acc[mi][ni][1] = 0.f;
            acc[mi][ni][2] = 0.f; acc[mi][ni][3] = 0.f;
        }

    const int scl  = t >> 3;   // cvt-phase: class row 0..63
    const int ssub = t & 7;    // 8 threads per row, 8 floats each

    for (int ks = 0; ks < NSTEP; ++ks) {
        const int p = ks & 1;
        __syncthreads();   // B1: fbuf[p] DMA complete; bbuf free for overwrite

        // --- cvt phase: fbuf[p] -> bbuf (each element once) + sumsq ---
        {
            const floatx4 f0 = *(const floatx4*)((const char*)&fbuf[p][0] + t * 32);
            const floatx4 f1 = *(const floatx4*)((const char*)&fbuf[p][0] + t * 32 + 16);
            float ss = f0[0]*f0[0] + f0[1]*f0[1] + f0[2]*f0[2] + f0[3]*f0[3]
                     + f1[0]*f1[0] + f1[1]*f1[1] + f1[2]*f1[2] + f1[3]*f1[3];
            ss += __shfl_xor(ss, 1);
            ss += __shfl_xor(ss, 2);
            ss += __shfl_xor(ss, 4);
            short8 br;
            br[0] = (short)f2bf(f0[0]); br[1] = (short)f2bf(f0[1]);
            br[2] = (short)f2bf(f0[2]); br[3] = (short)f2bf(f0[3]);
            br[4] = (short)f2bf(f1[0]); br[5] = (short)f2bf(f1[1]);
            br[6] = (short)f2bf(f1[2]); br[7] = (short)f2bf(f1[3]);
            const int gsw = ssub ^ (scl & 7);          // 16B-granule XOR swizzle
            *(short8*)(&bbuf[scl * BK + gsw * 8]) = br;
            if (ssub == 0) ssb[scl] += ss;             // one writer per class
        }
        __syncthreads();   // B2: bbuf + ssb(step) visible

        // issue DMA for step ks+1 into fbuf[p^1] (its last readers passed B1)
        if (ks + 1 < NSTEP) {
            const size_t so = (size_t)(ks + 1) * (BK * 4);
#pragma unroll
            for (int j = 0; j < 2; ++j)
                async_cp16(wbytes + goff[j] + so, (char*)&fbuf[p ^ 1][0] + ldsoff[j]);
        }

        // --- MFMA phase on bf16 tile ---
#pragma unroll
        for (int kk = 0; kk < 2; ++kk) {
            short8 a[4], b[4];
            const int kg = ks * BK + kk * 32 + quad * 8;
#pragma unroll
            for (int mi = 0; mi < 4; ++mi)
                a[mi] = *(const short8*)(xn + (size_t)(mbase + mi * 16 + nin) * DIM + kg);
#pragma unroll
            for (int ni = 0; ni < 4; ++ni) {
                const int cl = ni * 16 + nin;
                const int g = kk * 4 + quad;
                const int gsw = g ^ (cl & 7);
                b[ni] = *(const short8*)(&bbuf[cl * BK + gsw * 8]);
            }
#pragma unroll
            for (int mi = 0; mi < 4; ++mi)
#pragma unroll
                for (int ni = 0; ni < 4; ++ni)
                    acc[mi][ni] = __builtin_amdgcn_mfma_f32_16x16x32_bf16(
                        a[mi], b[ni], acc[mi][ni], 0, 0, 0);
        }
    }
    // ssb complete as of B2(last step); epilogue only reads it -> no extra barrier

    // --- epilogue: normalize, arcface transform, per-row exp-sum ---
    float rns[4];
#pragma unroll
    for (int ni = 0; ni < 4; ++ni)
        rns[ni] = 1.0f / fmaxf(sqrtf(ssb[ni * 16 + nin]), 1e-12f);

#pragma unroll
    for (int mi = 0; mi < 4; ++mi) {
#pragma unroll
        for (int reg = 0; reg < 4; ++reg) {
            const int m = mbase + mi * 16 + quad * 4 + reg;
            const int tg = target[m];
            float psum = 0.f;
#pragma unroll
            for (int ni = 0; ni < 4; ++ni) {
                const int c = c0 + ni * 16 + nin;
                if (c < NCLASS) {
                    const float cosv = acc[mi][ni][reg] * rns[ni];
                    float lg = S_SCALE * cosv;
                    if (c == tg) {
                        const float sine = sqrtf(fmaxf(1.f - cosv * cosv, 0.f));
                        float phi = cosv * COSM - sine * SINM;
                        if (!(cosv > 0.f)) phi = cosv;   // easy_margin
                        lg = S_SCALE * phi;
                        tlogit[m] = lg;
                    }
                    psum += __expf(lg - S_SCALE);        // fixed shift S (logit <= S)
                }
            }
            psum += __shfl_xor(psum, 1);
            psum += __shfl_xor(psum, 2);
            psum += __shfl_xor(psum, 4);
            psum += __shfl_xor(psum, 8);
            if (nin == 0)
                partials[(size_t)tile * BATCH + m] = psum;   // coalesced per block
        }
    }
}

// ---------------- Kernel 3a: per-row logsumexp + nll ----------------
__global__ void reduce_lse(const float* __restrict__ partials,
                           const float* __restrict__ tlogit,
                           float* __restrict__ nll) {
    const int m = blockIdx.x;
    const int t = threadIdx.x; // 256
    float s = 0.f;
    for (int b = t; b < NT; b += 256) s += partials[(size_t)b * BATCH + m];
#pragma unroll
    for (int d = 1; d < 64; d <<= 1) s += __shfl_xor(s, d);
    __shared__ float red[4];
    if ((t & 63) == 0) red[t >> 6] = s;
    __syncthreads();
    if (t == 0) {
        const float tot = red[0] + red[1] + red[2] + red[3];
        nll[m] = (logf(tot) + S_SCALE) - tlogit[m];
    }
}

// ---------------- Kernel 3b: mean ----------------
__global__ void reduce_mean(const float* __restrict__ nll, float* __restrict__ out) {
    const int t = threadIdx.x; // 512
    float s = nll[t];
#pragma unroll
    for (int d = 1; d < 64; d <<= 1) s += __shfl_xor(s, d);
    __shared__ float red[8];
    if ((t & 63) == 0) red[t >> 6] = s;
    __syncthreads();
    if (t == 0) {
        float tot = 0.f;
#pragma unroll
        for (int i = 0; i < 8; ++i) tot += red[i];
        out[0] = tot / (float)BATCH;
    }
}

extern "C" void kernel_launch(void* const* d_in, const int* in_sizes, int n_in,
                              void* d_out, int out_size, void* d_ws, size_t ws_size,
                              hipStream_t stream) {
    const float* x = (const float*)d_in[0];
    const float* w = (const float*)d_in[1];
    const int* target = (const int*)d_in[2];

    char* ws = (char*)d_ws;
    u16* xn         = (u16*)ws;
    float* tlogit   = (float*)(ws + 524288);
    float* nll      = (float*)(ws + 526336);
    float* partials = (float*)(ws + 528384);

    xnorm_kernel<<<BATCH, 64, 0, stream>>>(x, xn);
    arcface_main<<<NT, 512, 0, stream>>>(w, xn, target, partials, tlogit);
    reduce_lse<<<BATCH, 256, 0, stream>>>(partials, tlogit, nll);
    reduce_mean<<<1, 512, 0, stream>>>(nll, (float*)d_out);
}